// Round 16
// baseline (688.377 us; speedup 1.0000x reference)
//
#include <hip/hip_runtime.h>
#include <hip/hip_bf16.h>
#include <stdint.h>

// SwinTransformerBlock: B=8, H=W=128, C=256, NH=16, HD=16, WS=8, SS=4, HID=1024
// Tokens M = 131072, windows = 2048 (64 tokens each), N_qkv = 768.

#define SLOT ((size_t)64 << 20)  // 64 MiB slot (131072 * 256 * 2B)

typedef __attribute__((ext_vector_type(8))) short bf16x8;
typedef __attribute__((ext_vector_type(4))) float f32x4;

union FU { float f; unsigned u; };

__device__ inline float bflo(unsigned p) { FU x; x.u = p << 16; return x.f; }
__device__ inline float bfhi(unsigned p) { FU x; x.u = p & 0xffff0000u; return x.f; }

// native casts: compiler emits v_cvt_(pk_)bf16_f32 (m240: scalar cast is the
// fast path; manual bit-twiddle RNE defeats the fusion and costs ~8 VALU ops)
__device__ inline unsigned short f2bf(float f) {
  union { __hip_bfloat16 h; unsigned short u; } cv;
  cv.h = __float2bfloat16(f);
  return cv.u;
}
__device__ inline unsigned packbf2(float a, float b) {
  union { unsigned short s[2]; unsigned u; } cv;
  union { __hip_bfloat16 h; unsigned short u; } ca, cb;
  ca.h = __float2bfloat16(a);
  cb.h = __float2bfloat16(b);
  cv.s[0] = ca.u; cv.s[1] = cb.u;
  return cv.u;
}

// sigmoid GELU: x*sigmoid(1.702x); typical err ~0.005 here, well under threshold
__device__ inline float fast_gelu(float v) {
  return v / (1.0f + __expf(-1.702f * v));
}

// async global -> LDS, 16 bytes per lane
__device__ inline void gload16(const void* g, void* l) {
  __builtin_amdgcn_global_load_lds(
      (const __attribute__((address_space(1))) unsigned int*)g,
      (__attribute__((address_space(3))) unsigned int*)l, 16, 0, 0);
}

// ---------------- weight prep ----------------

// concat+transpose qkv weights, 0.25 q-scale folded in (exact: pow2 scale)
__global__ __launch_bounds__(256) void build_qkvw(
    const float* __restrict__ qw, const float* __restrict__ kw, const float* __restrict__ vw,
    const float* __restrict__ qb, const float* __restrict__ kb, const float* __restrict__ vb,
    unsigned short* __restrict__ wt, float* __restrict__ bias) {
  int i = blockIdx.x * 256 + threadIdx.x;  // over 768*256
  if (i < 768 * 256) {
    int n = i >> 8, c = i & 255;
    const float* w = (n < 256) ? qw : (n < 512 ? kw : vw);
    const float sc = (n < 256) ? 0.25f : 1.0f;
    int nn = n & 255;
    wt[i] = f2bf(sc * w[c * 256 + nn]);
  }
  if (i < 768) {
    bias[i] = (i < 256) ? 0.25f * qb[i] : (i < 512 ? kb[i - 256] : vb[i - 512]);
  }
}

// src [R][C] fp32 -> dst [C][R] bf16 (transpose + convert)
__global__ __launch_bounds__(256) void wconv_t(
    const float* __restrict__ src, unsigned short* __restrict__ dst, int R, int C) {
  int i = blockIdx.x * 256 + threadIdx.x;
  if (i >= R * C) return;
  int n = i / R, c = i - n * R;
  dst[i] = f2bf(src[(size_t)c * C + n]);
}

// ---------------- LN1 + roll + window partition ----------------
__global__ __launch_bounds__(256) void ln1_roll_win(
    const float* __restrict__ x, const float* __restrict__ g, const float* __restrict__ b,
    unsigned short* __restrict__ hwin) {
  const int tok = blockIdx.x * 4 + (threadIdx.x >> 6);
  const int l = threadIdx.x & 63;
  const int n = tok & 63, wi = (tok >> 6) & 255, bb = tok >> 14;
  const int wh = wi >> 4, ww = wi & 15, r = n >> 3, c = n & 7;
  const int hs = (wh * 8 + r + 4) & 127;    // roll(-4)
  const int wsx = (ww * 8 + c + 4) & 127;
  const float* xr = x + ((size_t)bb * 16384 + hs * 128 + wsx) * 256;
  float4 v = *(const float4*)(xr + l * 4);
  float s = v.x + v.y + v.z + v.w;
#pragma unroll
  for (int off = 32; off; off >>= 1) s += __shfl_xor(s, off);
  const float mean = s * (1.f / 256.f);
  const float d0 = v.x - mean, d1 = v.y - mean, d2 = v.z - mean, d3 = v.w - mean;
  float vv = d0 * d0 + d1 * d1 + d2 * d2 + d3 * d3;
#pragma unroll
  for (int off = 32; off; off >>= 1) vv += __shfl_xor(vv, off);
  const float rs = rsqrtf(vv * (1.f / 256.f) + 1e-5f);
  float4 gg = *(const float4*)(g + l * 4);
  float4 bv = *(const float4*)(b + l * 4);
  uint2 outv;
  outv.x = packbf2(d0 * rs * gg.x + bv.x, d1 * rs * gg.y + bv.y);
  outv.y = packbf2(d2 * rs * gg.z + bv.z, d3 * rs * gg.w + bv.w);
  *(uint2*)(hwin + (size_t)tok * 256 + l * 4) = outv;
}

// ---------------- 128x128-tile bf16 MFMA GEMM (r15 structure, proven) ----------------
template <int EPI, int K, int N, int NBX>
__global__ __launch_bounds__(256) void gemm128(
    const unsigned short* __restrict__ A, const unsigned short* __restrict__ Bt,
    const float* __restrict__ bias, unsigned short* __restrict__ Cb,
    float* __restrict__ Cf) {
  __shared__ __align__(16) unsigned short smem[2][2][128 * 64];  // 64KB
  const int nwg = gridDim.x;
  const int q = nwg >> 3;
  const int swz = (blockIdx.x & 7) * q + (blockIdx.x >> 3);
  const int m0 = (swz / NBX) * 128;
  const int n0 = (swz % NBX) * 128;

  const int t = threadIdx.x, w = t >> 6, l = t & 63;
  const int lg = l >> 4, lm = l & 15;
  const int wr = w >> 1, wc = w & 1;  // wave quadrant: rows wr*64, cols wc*64

  const int srow = w * 32 + (l >> 3);
  const int scol = ((l & 7) ^ (l >> 3)) * 8;
  const unsigned short* Ap = A + (size_t)(m0 + srow) * K + scol;
  const unsigned short* Bp = Bt + (size_t)(n0 + srow) * K + scol;

  const int cb = n0 + wc * 64 + lm;
  f32x4 acc[4][4];
#pragma unroll
  for (int n = 0; n < 4; ++n) {
    const float bv = bias[cb + n * 16];
#pragma unroll
    for (int m = 0; m < 4; ++m) acc[m][n] = (f32x4){bv, bv, bv, bv};
  }

  constexpr int NT = K >> 6;
  const int cx = lg ^ (lm & 7);  // read-side chunk base

#pragma unroll
  for (int i = 0; i < 4; ++i) {
    gload16(Ap + (size_t)(i * 8) * K, &smem[0][0][(w * 32 + i * 8) * 64]);
    gload16(Bp + (size_t)(i * 8) * K, &smem[0][1][(w * 32 + i * 8) * 64]);
  }
  __syncthreads();

#pragma unroll
  for (int kt = 0; kt < NT; ++kt) {
    const int cur = kt & 1;
    if (kt + 1 < NT) {
      const int ko = (kt + 1) << 6;
#pragma unroll
      for (int i = 0; i < 4; ++i) {
        gload16(Ap + (size_t)(i * 8) * K + ko, &smem[cur ^ 1][0][(w * 32 + i * 8) * 64]);
        gload16(Bp + (size_t)(i * 8) * K + ko, &smem[cur ^ 1][1][(w * 32 + i * 8) * 64]);
      }
    }
#pragma unroll
    for (int kk = 0; kk < 64; kk += 32) {
      const int ch = (cx ^ (kk >> 3)) * 8;
      bf16x8 af[4], bfr[4];
#pragma unroll
      for (int m = 0; m < 4; ++m)
        af[m] = *(const bf16x8*)&smem[cur][0][(wr * 64 + m * 16 + lm) * 64 + ch];
#pragma unroll
      for (int n = 0; n < 4; ++n)
        bfr[n] = *(const bf16x8*)&smem[cur][1][(wc * 64 + n * 16 + lm) * 64 + ch];
#pragma unroll
      for (int m = 0; m < 4; ++m)
#pragma unroll
        for (int n = 0; n < 4; ++n)
          acc[m][n] = __builtin_amdgcn_mfma_f32_16x16x32_bf16(af[m], bfr[n], acc[m][n], 0, 0, 0);
    }
    if (kt + 1 < NT) __syncthreads();
  }

  // ---- epilogue through LDS: 128x128 fp32, col ^= ((row>>2)&3)<<4 ----
  __syncthreads();
  float* Lp = (float*)smem;
#pragma unroll
  for (int m = 0; m < 4; ++m) {
#pragma unroll
    for (int n = 0; n < 4; ++n) {
      const int col = wc * 64 + n * 16 + lm;
#pragma unroll
      for (int r = 0; r < 4; ++r) {
        const int row = wr * 64 + m * 16 + lg * 4 + r;
        Lp[row * 128 + (col ^ (lg << 4))] = acc[m][n][r];
      }
    }
  }
  __syncthreads();
  if (EPI == 3) {
    const int rr0 = w * 32 + (l >> 5);
    const int cg = (l & 31) * 4;
#pragma unroll
    for (int p = 0; p < 16; ++p) {
      const int row = rr0 + p * 2;
      const int sc = cg ^ (((row >> 2) & 3) << 4);
      float4 v = *(const float4*)&Lp[row * 128 + sc];
      float4* op = (float4*)&Cf[(size_t)(m0 + row) * N + n0 + cg];
      float4 o = *op;
      o.x += v.x; o.y += v.y; o.z += v.z; o.w += v.w;
      *op = o;
    }
  } else {
    // widened bf16 path: 8 iters, 2 LDS float4 reads, one uint4 (8 bf16) store
    const int rw0 = w * 32 + (l >> 4);
    const int cg8 = (l & 15) * 8;
#pragma unroll
    for (int p = 0; p < 8; ++p) {
      const int row = rw0 + p * 4;
      const int swzk = ((row >> 2) & 3) << 4;  // wave-uniform
      float4 v0 = *(const float4*)&Lp[row * 128 + (cg8 ^ swzk)];
      float4 v1 = *(const float4*)&Lp[row * 128 + ((cg8 + 4) ^ swzk)];
      if (EPI == 2) {
        v0.x = fast_gelu(v0.x); v0.y = fast_gelu(v0.y);
        v0.z = fast_gelu(v0.z); v0.w = fast_gelu(v0.w);
        v1.x = fast_gelu(v1.x); v1.y = fast_gelu(v1.y);
        v1.z = fast_gelu(v1.z); v1.w = fast_gelu(v1.w);
      }
      uint4 pk4;
      pk4.x = packbf2(v0.x, v0.y);
      pk4.y = packbf2(v0.z, v0.w);
      pk4.z = packbf2(v1.x, v1.y);
      pk4.w = packbf2(v1.z, v1.w);
      *(uint4*)&Cb[(size_t)(m0 + row) * N + n0 + cg8] = pk4;
    }
  }
}

// ---------------- fused MLP: out += gelu(h2@W1+b1)@W2 + b2 ----------------
// r14 structure (passed correctness), now with native v_cvt casts on the
// huge fc1->Hs convert path (256 gelu + 128 packs/thread). Hidden tensor
// never touches HBM. Per block: 64 tokens, 4 waves, hidden in 4 chunks of
// 256. fc1 computes hidden TRANSPOSED via mfma(A=W1,B=A) -> D[h][tok] so
// lane regs = 4 consecutive h for one token -> vectorized uint2 Hs store
// (2-way max). fc2 reads Hs rows as A-frags, W2 rows from L2, accumulates
// out[tok][c] (bias-init) across chunks. Epilogue: fp32 LDS transpose + RMW.
__global__ __launch_bounds__(256, 2) void fused_mlp(
    const unsigned short* __restrict__ h2, const unsigned short* __restrict__ w1t,
    const float* __restrict__ b1, const unsigned short* __restrict__ w2t,
    const float* __restrict__ b2, float* __restrict__ out) {
  __shared__ __align__(16) unsigned short smem[2 * 64 * 256];  // 64 KB
  unsigned short* As = smem;             // [64 tok][256 k], chunk^(row&7) swz
  unsigned short* Hs = smem + 64 * 256;  // [64 tok][256 h], 8B-chunk^((tok&7)<<1)
  const int nwg = gridDim.x;             // 2048
  const int q = nwg >> 3;
  const int swz = (blockIdx.x & 7) * q + (blockIdx.x >> 3);
  const int m0 = swz * 64;

  const int t = threadIdx.x, w = t >> 6, l = t & 63;
  const int lg = l >> 4, lm = l & 15;

  // ---- stage A (64x256 bf16): LDS[r][c16] = G[r][c16 ^ (r&7)] ----
#pragma unroll
  for (int i = 0; i < 8; ++i) {
    const int row = w * 16 + i * 2 + (l >> 5);
    const int sc = (l & 31) ^ (row & 7);
    gload16(h2 + (size_t)(m0 + row) * 256 + sc * 8, &As[(w * 16 + i * 2) * 256]);
  }

  f32x4 oacc[4][4];  // out: rows = 64 tokens, cols = w*64 + n*16+lm
#pragma unroll
  for (int n = 0; n < 4; ++n) {
    const float bv = b2[w * 64 + n * 16 + lm];
#pragma unroll
    for (int m = 0; m < 4; ++m) oacc[m][n] = (f32x4){bv, bv, bv, bv};
  }
  __syncthreads();

  for (int hc = 0; hc < 4; ++hc) {
    if (hc) __syncthreads();  // prior fc2 reads of Hs complete
    // ---- fc1: D[h][tok] for h-slice hc*256 + w*64 .. +64 ----
    f32x4 a1[4][4];
#pragma unroll
    for (int mh = 0; mh < 4; ++mh)
#pragma unroll
      for (int nt = 0; nt < 4; ++nt) a1[mh][nt] = (f32x4){0.f, 0.f, 0.f, 0.f};
#pragma unroll
    for (int kk = 0; kk < 8; ++kk) {
      bf16x8 aw[4], bt[4];
#pragma unroll
      for (int mh = 0; mh < 4; ++mh)
        aw[mh] = *(const bf16x8*)(w1t +
                 (size_t)(hc * 256 + w * 64 + mh * 16 + lm) * 256 + kk * 32 + lg * 8);
#pragma unroll
      for (int nt = 0; nt < 4; ++nt) {
        const int c2 = (kk * 4 + lg) ^ (lm & 7);
        bt[nt] = *(const bf16x8*)&As[(nt * 16 + lm) * 256 + c2 * 8];
      }
#pragma unroll
      for (int mh = 0; mh < 4; ++mh)
#pragma unroll
        for (int nt = 0; nt < 4; ++nt)
          a1[mh][nt] = __builtin_amdgcn_mfma_f32_16x16x32_bf16(aw[mh], bt[nt], a1[mh][nt], 0, 0, 0);
    }
    // ---- bias + gelu + pack -> Hs[tok][h] (vectorized uint2) ----
#pragma unroll
    for (int mh = 0; mh < 4; ++mh) {
      const float4 b1f = *(const float4*)&b1[hc * 256 + w * 64 + mh * 16 + lg * 4];
#pragma unroll
      for (int nt = 0; nt < 4; ++nt) {
        const int tok = nt * 16 + lm;
        const int cp = (w * 16 + mh * 4 + lg) ^ ((lm & 7) << 1);
        uint2 pk;
        pk.x = packbf2(fast_gelu(a1[mh][nt][0] + b1f.x), fast_gelu(a1[mh][nt][1] + b1f.y));
        pk.y = packbf2(fast_gelu(a1[mh][nt][2] + b1f.z), fast_gelu(a1[mh][nt][3] + b1f.w));
        *(uint2*)((char*)Hs + tok * 512 + cp * 8) = pk;
      }
    }
    __syncthreads();  // Hs published
    // ---- fc2: oacc += Hs @ W2[hc-slice] ----
#pragma unroll
    for (int kk = 0; kk < 8; ++kk) {
      bf16x8 ah[4], bw2[4];
#pragma unroll
      for (int mt = 0; mt < 4; ++mt) {
        const int tok = mt * 16 + lm;
        const int cp = (kk * 8 + lg * 2) ^ ((lm & 7) << 1);  // even-preserving
        ah[mt] = *(const bf16x8*)((const char*)Hs + tok * 512 + cp * 8);
      }
#pragma unroll
      for (int n = 0; n < 4; ++n)
        bw2[n] = *(const bf16x8*)(w2t +
                 (size_t)(w * 64 + n * 16 + lm) * 1024 + hc * 256 + kk * 32 + lg * 8);
#pragma unroll
      for (int mt = 0; mt < 4; ++mt)
#pragma unroll
        for (int n = 0; n < 4; ++n)
          oacc[mt][n] = __builtin_amdgcn_mfma_f32_16x16x32_bf16(ah[mt], bw2[n], oacc[mt][n], 0, 0, 0);
    }
  }

  // ---- epilogue: fp32 LDS transpose (Lt overlays As+Hs), float4 RMW ----
  __syncthreads();
  float* Lt = (float*)smem;  // 64 x 256 fp32 = 64 KB
#pragma unroll
  for (int m = 0; m < 4; ++m)
#pragma unroll
    for (int n = 0; n < 4; ++n) {
      const int col = w * 64 + n * 16 + lm;
#pragma unroll
      for (int r = 0; r < 4; ++r) {
        const int row = m * 16 + lg * 4 + r;  // (row>>2)&3 == lg
        Lt[row * 256 + (col ^ (lg << 4))] = oacc[m][n][r];
      }
    }
  __syncthreads();
#pragma unroll
  for (int p = 0; p < 16; ++p) {
    const int fidx = p * 256 + t;
    const int row = fidx >> 6;          // 64 float4 per 256-col row
    const int c4 = (fidx & 63) * 4;
    const int sc = c4 ^ (((row >> 2) & 3) << 4);
    float4 v = *(const float4*)&Lt[row * 256 + sc];
    float4* op = (float4*)&out[(size_t)(m0 + row) * 256 + c4];
    float4 o = *op;
    o.x += v.x; o.y += v.y; o.z += v.z; o.w += v.w;
    *op = o;
  }
}

// ---------------- proj + window-reverse + residual + LN2 (fused, proven r12) ----------------
__global__ __launch_bounds__(512, 2) void proj_ln2(
    const unsigned short* __restrict__ A, const unsigned short* __restrict__ Bt,
    const float* __restrict__ bias, const float* __restrict__ x,
    const float* __restrict__ g2, const float* __restrict__ b2,
    float* __restrict__ out, unsigned short* __restrict__ h2) {
  constexpr int K = 256;
  __shared__ __align__(16) unsigned short smem[2][2][256 * 64];  // 128 KB
  const int nwg = gridDim.x;  // 512
  const int q = nwg >> 3;
  const int swz = (blockIdx.x & 7) * q + (blockIdx.x >> 3);
  const int m0 = swz * 256;

  const int t = threadIdx.x, w = t >> 6, l = t & 63;
  const int lg = l >> 4, lm = l & 15;
  const int wr = w >> 2, wn = w & 3;  // wave tile: rows wr*128, cols wn*64

  const int srow = w * 8 + (l >> 3);
  const int scol = ((l & 7) ^ (l >> 3)) * 8;
  const unsigned short* Ap = A + (size_t)(m0 + srow) * K + scol;
  const unsigned short* Bp = Bt + (size_t)srow * K + scol;

  f32x4 acc[8][4];
#pragma unroll
  for (int n = 0; n < 4; ++n) {
    const float bv = bias[wn * 64 + n * 16 + lm];
#pragma unroll
    for (int m = 0; m < 8; ++m) acc[m][n] = (f32x4){bv, bv, bv, bv};
  }

  const int cx = lg ^ (lm & 7);

#pragma unroll
  for (int i = 0; i < 4; ++i) {
    gload16(Ap + (size_t)(i * 64) * K, &smem[0][0][(i * 64 + w * 8) * 64]);
    gload16(Bp + (size_t)(i * 64) * K, &smem[0][1][(i * 64 + w * 8) * 64]);
  }
  __syncthreads();

#pragma unroll
  for (int kt = 0; kt < 4; ++kt) {
    const int cur = kt & 1;
    if (kt + 1 < 4) {
      const int ko = (kt + 1) << 6;
#pragma unroll
      for (int i = 0; i < 4; ++i) {
        gload16(Ap + (size_t)(i * 64) * K + ko, &smem[cur ^ 1][0][(i * 64 + w * 8) * 64]);
        gload16(Bp + (size_t)(i * 64) * K + ko, &smem[cur ^ 1][1][(i * 64 + w * 8) * 64]);
      }
    }
#pragma unroll
    for (int kk = 0; kk < 64; kk += 32) {
      const int ch = (cx ^ (kk >> 3)) * 8;
      bf16x8 af[8], bfr[4];
#pragma unroll
      for (int m = 0; m < 8; ++m)
        af[m] = *(const bf16x8*)&smem[cur][0][(wr * 128 + m * 16 + lm) * 64 + ch];
#pragma unroll
      for (int n = 0; n < 4; ++n)
        bfr[n] = *(const bf16x8*)&smem[cur][1][(wn * 64 + n * 16 + lm) * 64 + ch];
#pragma unroll
      for (int m = 0; m < 8; ++m)
#pragma unroll
        for (int n = 0; n < 4; ++n)
          acc[m][n] = __builtin_amdgcn_mfma_f32_16x16x32_bf16(af[m], bfr[n], acc[m][n], 0, 0, 0);
    }
    if (kt + 1 < 4) __syncthreads();
  }

  // ---- fused epilogue: two 128-row passes; one wave per row ----
  float* Lf = (float*)smem;  // 128 x 256 fp32 = 128 KB
  const float4 g4 = *(const float4*)(g2 + l * 4);
  const float4 bb4 = *(const float4*)(b2 + l * 4);
#pragma unroll
  for (int h = 0; h < 2; ++h) {
    __syncthreads();
    if (wr == h) {
#pragma unroll
      for (int m = 0; m < 8; ++m)
#pragma unroll
        for (int n = 0; n < 4; ++n) {
          const int col = wn * 64 + n * 16 + lm;
#pragma unroll
          for (int r = 0; r < 4; ++r) {
            const int rowl = m * 16 + lg * 4 + r;  // (rowl>>2)&3 == lg
            Lf[rowl * 256 + (col ^ (lg << 4))] = acc[m][n][r];
          }
        }
    }
    __syncthreads();
#pragma unroll
    for (int it = 0; it < 16; ++it) {
      const int rowl = it * 8 + w;
      const int sc = (l * 4) ^ (((rowl >> 2) & 3) << 4);
      float4 v = *(const float4*)&Lf[rowl * 256 + sc];
      // src window-token -> dst natural token (inverse of ln1's gather)
      const int src = m0 + h * 128 + rowl;
      const int bb = src >> 14, wi = (src >> 6) & 255, n = src & 63;
      const int hy = ((wi >> 4) * 8 + (n >> 3) + 4) & 127;
      const int wx = ((wi & 15) * 8 + (n & 7) + 4) & 127;
      const size_t dst = ((size_t)(bb << 14) + hy * 128 + wx) * 256;
      float4 xv = *(const float4*)(x + dst + l * 4);
      const float y0 = xv.x + v.x, y1 = xv.y + v.y;
      const float y2 = xv.z + v.z, y3 = xv.w + v.w;
      *(float4*)(out + dst + l * 4) = make_float4(y0, y1, y2, y3);
      float s = y0 + y1 + y2 + y3;
#pragma unroll
      for (int off = 32; off; off >>= 1) s += __shfl_xor(s, off);
      const float mean = s * (1.f / 256.f);
      const float d0 = y0 - mean, d1 = y1 - mean, d2 = y2 - mean, d3 = y3 - mean;
      float vv = d0 * d0 + d1 * d1 + d2 * d2 + d3 * d3;
#pragma unroll
      for (int off = 32; off; off >>= 1) vv += __shfl_xor(vv, off);
      const float rs = rsqrtf(vv * (1.f / 256.f) + 1e-5f);
      uint2 outv;
      outv.x = packbf2(d0 * rs * g4.x + bb4.x, d1 * rs * g4.y + bb4.y);
      outv.y = packbf2(d2 * rs * g4.z + bb4.z, d3 * rs * g4.w + bb4.w);
      *(uint2*)(h2 + dst + l * 4) = outv;
    }
  }
}

// ---------------- windowed attention, MFMA (16x16x32, verified layout) ----------------
__global__ __launch_bounds__(256) void attn_mfma(
    const unsigned short* __restrict__ qkv, const float* __restrict__ rpb,
    unsigned short* __restrict__ o) {
  __shared__ float rps[16][226];                      // [head][225 bias values]
  __shared__ __align__(16) unsigned short Pl[4][64][72];  // per-wave P [query][key]
  const int win = blockIdx.x;
  const int wh = (win >> 4) & 15, ww = win & 15;
  const int t = threadIdx.x, wv = t >> 6, l = t & 63;
  const int lg = l >> 4, lm = l & 15;
  const unsigned short* base = qkv + (size_t)win * 64 * 768;

  for (int i = t; i < 3600; i += 256) rps[i & 15][i >> 4] = rpb[i];  // rpb[idx][h]
  __syncthreads();

  const bool eH = (wh == 15), eW = (ww == 15);
  const bool edge = eH || eW;

  int qv[4], liq[4];
#pragma unroll
  for (int nt = 0; nt < 4; ++nt) {
    const int qn = nt * 16 + lm, ri = qn >> 3, ci = qn & 7;
    qv[nt] = ri * 15 + ci;
    liq[nt] = (eH ? (ri < 4 ? 1 : 2) : 0) * 3 + (eW ? (ci < 4 ? 1 : 2) : 0);
  }
  int kv[4][4], ljk[4][4];
#pragma unroll
  for (int mt = 0; mt < 4; ++mt)
#pragma unroll
    for (int r = 0; r < 4; ++r) {
      const int kn = mt * 16 + 4 * lg + r, rj = kn >> 3, cj = kn & 7;
      kv[mt][r] = rj * 15 + cj;
      ljk[mt][r] = (eH ? (rj < 4 ? 1 : 2) : 0) * 3 + (eW ? (cj < 4 ? 1 : 2) : 0);
    }

  const bf16x8 zf = {0, 0, 0, 0, 0, 0, 0, 0};

#pragma unroll 1
  for (int hi = 0; hi < 4; ++hi) {
    const int h = wv * 4 + hi;
    bf16x8 kf[4], qf[4];
#pragma unroll
    for (int i = 0; i < 4; ++i) {
      kf[i] = (lg < 2)
          ? *(const bf16x8*)(base + (size_t)(i * 16 + lm) * 768 + 256 + h * 16 + lg * 8)
          : zf;
      qf[i] = (lg < 2)
          ? *(const bf16x8*)(base + (size_t)(i * 16 + lm) * 768 + h * 16 + lg * 8)
          : zf;
    }
    f32x4 acc[4][4];  // [mt=key tile][nt=query tile]
#pragma unroll
    for (int mt = 0; mt < 4; ++mt)
#pragma unroll
      for (int nt = 0; nt < 4; ++nt)
        acc[mt][nt] = (f32x4){0.f, 0.f, 0.f, 0.f};
#pragma unroll
    for (int mt = 0; mt < 4; ++mt)
#pragma unroll
      for (int nt = 0; nt < 4; ++nt)
        acc[mt][nt] = __builtin_amdgcn_mfma_f32_16x16x32_bf16(kf[mt], qf[nt], acc[mt][nt], 0, 0, 0);

#pragma unroll
    for (int nt = 0; nt < 4; ++nt) {
      float mx = -1e30f;
#pragma unroll
      for (int mt = 0; mt < 4; ++mt)
#pragma unroll
        for (int r = 0; r < 4; ++r) {
          float s = acc[mt][nt][r] + rps[h][qv[nt] - kv[mt][r] + 112];
          if (edge) s += (liq[nt] == ljk[mt][r]) ? 0.f : -100.f;
          acc[mt][nt][r] = s;
          mx = fmaxf(mx, s);
        }
      mx = fmaxf(mx, __shfl_xor(mx, 16));
      mx = fmaxf(mx, __shfl_xor(mx, 32));
      float sum = 0.f;
#pragma unroll
      for (int mt = 0; mt < 4; ++mt)
#pragma unroll
        for (int r = 0; r < 4; ++r) {
          const float p = __expf(acc[mt][nt][r] - mx);
          acc[mt][nt][r] = p;
          sum += p;
        }
      sum += __shfl_xor(sum, 16);
      sum += __shfl_xor(sum, 32);
      const float inv = 1.f / sum;
      const int qn = nt * 16 + lm;
#pragma unroll
      for (int mt = 0; mt < 4; ++mt) {
        uint2 pk;
        pk.x = packbf2(acc[mt][nt][0] * inv, acc[mt][nt][1] * inv);
        pk.y = packbf2(acc[mt][nt][2] * inv, acc[mt][nt][3] * inv);
        *(uint2*)&Pl[wv][qn][mt * 16 + 4 * lg] = pk;
      }
    }

    f32x4 oacc[4];
#pragma unroll
    for (int mt = 0; mt < 4; ++mt) oacc[mt] = (f32x4){0.f, 0.f, 0.f, 0.f};
#pragma unroll
    for (int kk = 0; kk < 2; ++kk) {
      bf16x8 vf;
#pragma unroll
      for (int j = 0; j < 8; ++j)
        vf[j] = (short)base[(size_t)(kk * 32 + lg * 8 + j) * 768 + 512 + h * 16 + lm];
#pragma unroll
      for (int mt = 0; mt < 4; ++mt) {
        bf16x8 pf = *(const bf16x8*)&Pl[wv][mt * 16 + lm][kk * 32 + lg * 8];
        oacc[mt] = __builtin_amdgcn_mfma_f32_16x16x32_bf16(pf, vf, oacc[mt], 0, 0, 0);
      }
    }
#pragma unroll
    for (int mt = 0; mt < 4; ++mt)
#pragma unroll
      for (int r = 0; r < 4; ++r)
        o[((size_t)win * 64 + mt * 16 + 4 * lg + r) * 256 + h * 16 + lm] = f2bf(oacc[mt][r]);
  }
}

// ---------------- launch ----------------

extern "C" void kernel_launch(void* const* d_in, const int* in_sizes, int n_in,
                              void* d_out, int out_size, void* d_ws, size_t ws_size,
                              hipStream_t stream) {
  const float* x = (const float*)d_in[0];
  const float* ln1g = (const float*)d_in[1];
  const float* ln1b = (const float*)d_in[2];
  const float* qw = (const float*)d_in[3];
  const float* qb = (const float*)d_in[4];
  const float* kw = (const float*)d_in[5];
  const float* kb = (const float*)d_in[6];
  const float* vw = (const float*)d_in[7];
  const float* vb = (const float*)d_in[8];
  const float* rpb = (const float*)d_in[9];
  const float* pw = (const float*)d_in[10];
  const float* pb = (const float*)d_in[11];
  const float* ln2g = (const float*)d_in[12];
  const float* ln2b = (const float*)d_in[13];
  const float* f1w = (const float*)d_in[14];
  const float* f1b = (const float*)d_in[15];
  const float* f2w = (const float*)d_in[16];
  const float* f2b = (const float*)d_in[17];
  float* out = (float*)d_out;

  // workspace layout (lifetime-reused 64MiB slots):
  //   S0: hwin(ln1 out) -> h2 ; S1-3: qkv ; S4: o(attn out) ; weights at 5*SLOT.
  char* wsb = (char*)d_ws;
  unsigned short* hwin = (unsigned short*)(wsb);
  unsigned short* qkv = (unsigned short*)(wsb + SLOT);
  unsigned short* ovec = (unsigned short*)(wsb + 4 * SLOT);
  unsigned short* wqkvt = (unsigned short*)(wsb + 5 * SLOT);   // 768*256
  unsigned short* projt = wqkvt + 768 * 256;                   // 256*256
  unsigned short* fc1t = projt + 256 * 256;                    // 1024*256
  unsigned short* fc2t = fc1t + 1024 * 256;                    // 256*1024
  float* bqkv = (float*)(fc2t + 256 * 1024);                   // 768

  build_qkvw<<<768, 256, 0, stream>>>(qw, kw, vw, qb, kb, vb, wqkvt, bqkv);
  wconv_t<<<256, 256, 0, stream>>>(pw, projt, 256, 256);
  wconv_t<<<1024, 256, 0, stream>>>(f1w, fc1t, 256, 1024);
  wconv_t<<<1024, 256, 0, stream>>>(f2w, fc2t, 1024, 256);

  ln1_roll_win<<<32768, 256, 0, stream>>>(x, ln1g, ln1b, hwin);
  // fused QKV: M=131072, N=768, K=256 (q-scale folded into weights)
  gemm128<0, 256, 768, 6><<<6 * 1024, 256, 0, stream>>>(hwin, wqkvt, bqkv, qkv, nullptr);
  attn_mfma<<<2048, 256, 0, stream>>>(qkv, rpb, ovec);  // o -> S4
  // proj + window-reverse + residual + LN2: x2 -> d_out, h2 -> S0
  proj_ln2<<<512, 512, 0, stream>>>(ovec, projt, pb, x, ln2g, ln2b, out, hwin);
  // fused MLP: out += gelu(h2@W1+b1)@W2 + b2 (hidden never touches HBM)
  fused_mlp<<<2048, 256, 0, stream>>>(hwin, fc1t, f1b, fc2t, f2b, out);
}

// Round 17
// 668.943 us; speedup vs baseline: 1.0291x; 1.0291x over previous
//
#include <hip/hip_runtime.h>
#include <hip/hip_bf16.h>
#include <stdint.h>

// SwinTransformerBlock: B=8, H=W=128, C=256, NH=16, HD=16, WS=8, SS=4, HID=1024
// Tokens M = 131072, windows = 2048 (64 tokens each), N_qkv = 768.

#define SLOT ((size_t)64 << 20)  // 64 MiB slot (131072 * 256 * 2B)

typedef __attribute__((ext_vector_type(8))) short bf16x8;
typedef __attribute__((ext_vector_type(4))) float f32x4;

union FU { float f; unsigned u; };

__device__ inline float bflo(unsigned p) { FU x; x.u = p << 16; return x.f; }
__device__ inline float bfhi(unsigned p) { FU x; x.u = p & 0xffff0000u; return x.f; }

// native casts: compiler emits v_cvt_(pk_)bf16_f32 (manual bit-twiddle RNE
// defeats the fusion and costs ~8 VALU ops)
__device__ inline unsigned short f2bf(float f) {
  union { __hip_bfloat16 h; unsigned short u; } cv;
  cv.h = __float2bfloat16(f);
  return cv.u;
}
__device__ inline unsigned packbf2(float a, float b) {
  union { unsigned short s[2]; unsigned u; } cv;
  union { __hip_bfloat16 h; unsigned short u; } ca, cb;
  ca.h = __float2bfloat16(a);
  cb.h = __float2bfloat16(b);
  cv.s[0] = ca.u; cv.s[1] = cb.u;
  return cv.u;
}

// sigmoid GELU: x*sigmoid(1.702x); typical err ~0.005 here, well under threshold
__device__ inline float fast_gelu(float v) {
  return v / (1.0f + __expf(-1.702f * v));
}

// async global -> LDS, 16 bytes per lane
__device__ inline void gload16(const void* g, void* l) {
  __builtin_amdgcn_global_load_lds(
      (const __attribute__((address_space(1))) unsigned int*)g,
      (__attribute__((address_space(3))) unsigned int*)l, 16, 0, 0);
}

// ---------------- weight prep ----------------

// concat+transpose qkv weights, 0.25 q-scale folded in (exact: pow2 scale)
__global__ __launch_bounds__(256) void build_qkvw(
    const float* __restrict__ qw, const float* __restrict__ kw, const float* __restrict__ vw,
    const float* __restrict__ qb, const float* __restrict__ kb, const float* __restrict__ vb,
    unsigned short* __restrict__ wt, float* __restrict__ bias) {
  int i = blockIdx.x * 256 + threadIdx.x;  // over 768*256
  if (i < 768 * 256) {
    int n = i >> 8, c = i & 255;
    const float* w = (n < 256) ? qw : (n < 512 ? kw : vw);
    const float sc = (n < 256) ? 0.25f : 1.0f;
    int nn = n & 255;
    wt[i] = f2bf(sc * w[c * 256 + nn]);
  }
  if (i < 768) {
    bias[i] = (i < 256) ? 0.25f * qb[i] : (i < 512 ? kb[i - 256] : vb[i - 512]);
  }
}

// src [R][C] fp32 -> dst [C][R] bf16 (transpose + convert)
__global__ __launch_bounds__(256) void wconv_t(
    const float* __restrict__ src, unsigned short* __restrict__ dst, int R, int C) {
  int i = blockIdx.x * 256 + threadIdx.x;
  if (i >= R * C) return;
  int n = i / R, c = i - n * R;
  dst[i] = f2bf(src[(size_t)c * C + n]);
}

// ---------------- LN1 + roll + window partition ----------------
__global__ __launch_bounds__(256) void ln1_roll_win(
    const float* __restrict__ x, const float* __restrict__ g, const float* __restrict__ b,
    unsigned short* __restrict__ hwin) {
  const int tok = blockIdx.x * 4 + (threadIdx.x >> 6);
  const int l = threadIdx.x & 63;
  const int n = tok & 63, wi = (tok >> 6) & 255, bb = tok >> 14;
  const int wh = wi >> 4, ww = wi & 15, r = n >> 3, c = n & 7;
  const int hs = (wh * 8 + r + 4) & 127;    // roll(-4)
  const int wsx = (ww * 8 + c + 4) & 127;
  const float* xr = x + ((size_t)bb * 16384 + hs * 128 + wsx) * 256;
  float4 v = *(const float4*)(xr + l * 4);
  float s = v.x + v.y + v.z + v.w;
#pragma unroll
  for (int off = 32; off; off >>= 1) s += __shfl_xor(s, off);
  const float mean = s * (1.f / 256.f);
  const float d0 = v.x - mean, d1 = v.y - mean, d2 = v.z - mean, d3 = v.w - mean;
  float vv = d0 * d0 + d1 * d1 + d2 * d2 + d3 * d3;
#pragma unroll
  for (int off = 32; off; off >>= 1) vv += __shfl_xor(vv, off);
  const float rs = rsqrtf(vv * (1.f / 256.f) + 1e-5f);
  float4 gg = *(const float4*)(g + l * 4);
  float4 bv = *(const float4*)(b + l * 4);
  uint2 outv;
  outv.x = packbf2(d0 * rs * gg.x + bv.x, d1 * rs * gg.y + bv.y);
  outv.y = packbf2(d2 * rs * gg.z + bv.z, d3 * rs * gg.w + bv.w);
  *(uint2*)(hwin + (size_t)tok * 256 + l * 4) = outv;
}

// ---------------- 128x128-tile bf16 MFMA GEMM (r15 structure, proven best) ----------------
template <int EPI, int K, int N, int NBX>
__global__ __launch_bounds__(256) void gemm128(
    const unsigned short* __restrict__ A, const unsigned short* __restrict__ Bt,
    const float* __restrict__ bias, unsigned short* __restrict__ Cb,
    float* __restrict__ Cf) {
  __shared__ __align__(16) unsigned short smem[2][2][128 * 64];  // 64KB
  const int nwg = gridDim.x;
  const int q = nwg >> 3;
  const int swz = (blockIdx.x & 7) * q + (blockIdx.x >> 3);
  const int m0 = (swz / NBX) * 128;
  const int n0 = (swz % NBX) * 128;

  const int t = threadIdx.x, w = t >> 6, l = t & 63;
  const int lg = l >> 4, lm = l & 15;
  const int wr = w >> 1, wc = w & 1;  // wave quadrant: rows wr*64, cols wc*64

  const int srow = w * 32 + (l >> 3);
  const int scol = ((l & 7) ^ (l >> 3)) * 8;
  const unsigned short* Ap = A + (size_t)(m0 + srow) * K + scol;
  const unsigned short* Bp = Bt + (size_t)(n0 + srow) * K + scol;

  const int cb = n0 + wc * 64 + lm;
  f32x4 acc[4][4];
#pragma unroll
  for (int n = 0; n < 4; ++n) {
    const float bv = bias[cb + n * 16];
#pragma unroll
    for (int m = 0; m < 4; ++m) acc[m][n] = (f32x4){bv, bv, bv, bv};
  }

  constexpr int NT = K >> 6;
  const int cx = lg ^ (lm & 7);  // read-side chunk base

#pragma unroll
  for (int i = 0; i < 4; ++i) {
    gload16(Ap + (size_t)(i * 8) * K, &smem[0][0][(w * 32 + i * 8) * 64]);
    gload16(Bp + (size_t)(i * 8) * K, &smem[0][1][(w * 32 + i * 8) * 64]);
  }
  __syncthreads();

#pragma unroll
  for (int kt = 0; kt < NT; ++kt) {
    const int cur = kt & 1;
    if (kt + 1 < NT) {
      const int ko = (kt + 1) << 6;
#pragma unroll
      for (int i = 0; i < 4; ++i) {
        gload16(Ap + (size_t)(i * 8) * K + ko, &smem[cur ^ 1][0][(w * 32 + i * 8) * 64]);
        gload16(Bp + (size_t)(i * 8) * K + ko, &smem[cur ^ 1][1][(w * 32 + i * 8) * 64]);
      }
    }
#pragma unroll
    for (int kk = 0; kk < 64; kk += 32) {
      const int ch = (cx ^ (kk >> 3)) * 8;
      bf16x8 af[4], bfr[4];
#pragma unroll
      for (int m = 0; m < 4; ++m)
        af[m] = *(const bf16x8*)&smem[cur][0][(wr * 64 + m * 16 + lm) * 64 + ch];
#pragma unroll
      for (int n = 0; n < 4; ++n)
        bfr[n] = *(const bf16x8*)&smem[cur][1][(wc * 64 + n * 16 + lm) * 64 + ch];
#pragma unroll
      for (int m = 0; m < 4; ++m)
#pragma unroll
        for (int n = 0; n < 4; ++n)
          acc[m][n] = __builtin_amdgcn_mfma_f32_16x16x32_bf16(af[m], bfr[n], acc[m][n], 0, 0, 0);
    }
    if (kt + 1 < NT) __syncthreads();
  }

  // ---- epilogue through LDS: 128x128 fp32, col ^= ((row>>2)&3)<<4 ----
  __syncthreads();
  float* Lp = (float*)smem;
#pragma unroll
  for (int m = 0; m < 4; ++m) {
#pragma unroll
    for (int n = 0; n < 4; ++n) {
      const int col = wc * 64 + n * 16 + lm;
#pragma unroll
      for (int r = 0; r < 4; ++r) {
        const int row = wr * 64 + m * 16 + lg * 4 + r;
        Lp[row * 128 + (col ^ (lg << 4))] = acc[m][n][r];
      }
    }
  }
  __syncthreads();
  if (EPI == 3) {
    const int rr0 = w * 32 + (l >> 5);
    const int cg = (l & 31) * 4;
#pragma unroll
    for (int p = 0; p < 16; ++p) {
      const int row = rr0 + p * 2;
      const int sc = cg ^ (((row >> 2) & 3) << 4);
      float4 v = *(const float4*)&Lp[row * 128 + sc];
      float4* op = (float4*)&Cf[(size_t)(m0 + row) * N + n0 + cg];
      float4 o = *op;
      o.x += v.x; o.y += v.y; o.z += v.z; o.w += v.w;
      *op = o;
    }
  } else {
    // widened bf16 path: 8 iters, 2 LDS float4 reads, one uint4 (8 bf16) store
    const int rw0 = w * 32 + (l >> 4);
    const int cg8 = (l & 15) * 8;
#pragma unroll
    for (int p = 0; p < 8; ++p) {
      const int row = rw0 + p * 4;
      const int swzk = ((row >> 2) & 3) << 4;  // wave-uniform
      float4 v0 = *(const float4*)&Lp[row * 128 + (cg8 ^ swzk)];
      float4 v1 = *(const float4*)&Lp[row * 128 + ((cg8 + 4) ^ swzk)];
      if (EPI == 2) {
        v0.x = fast_gelu(v0.x); v0.y = fast_gelu(v0.y);
        v0.z = fast_gelu(v0.z); v0.w = fast_gelu(v0.w);
        v1.x = fast_gelu(v1.x); v1.y = fast_gelu(v1.y);
        v1.z = fast_gelu(v1.z); v1.w = fast_gelu(v1.w);
      }
      uint4 pk4;
      pk4.x = packbf2(v0.x, v0.y);
      pk4.y = packbf2(v0.z, v0.w);
      pk4.z = packbf2(v1.x, v1.y);
      pk4.w = packbf2(v1.z, v1.w);
      *(uint4*)&Cb[(size_t)(m0 + row) * N + n0 + cg8] = pk4;
    }
  }
}

// ---------------- proj + window-reverse + residual + LN2 (fused, proven r12) ----------------
__global__ __launch_bounds__(512, 2) void proj_ln2(
    const unsigned short* __restrict__ A, const unsigned short* __restrict__ Bt,
    const float* __restrict__ bias, const float* __restrict__ x,
    const float* __restrict__ g2, const float* __restrict__ b2,
    float* __restrict__ out, unsigned short* __restrict__ h2) {
  constexpr int K = 256;
  __shared__ __align__(16) unsigned short smem[2][2][256 * 64];  // 128 KB
  const int nwg = gridDim.x;  // 512
  const int q = nwg >> 3;
  const int swz = (blockIdx.x & 7) * q + (blockIdx.x >> 3);
  const int m0 = swz * 256;

  const int t = threadIdx.x, w = t >> 6, l = t & 63;
  const int lg = l >> 4, lm = l & 15;
  const int wr = w >> 2, wn = w & 3;  // wave tile: rows wr*128, cols wn*64

  const int srow = w * 8 + (l >> 3);
  const int scol = ((l & 7) ^ (l >> 3)) * 8;
  const unsigned short* Ap = A + (size_t)(m0 + srow) * K + scol;
  const unsigned short* Bp = Bt + (size_t)srow * K + scol;

  f32x4 acc[8][4];
#pragma unroll
  for (int n = 0; n < 4; ++n) {
    const float bv = bias[wn * 64 + n * 16 + lm];
#pragma unroll
    for (int m = 0; m < 8; ++m) acc[m][n] = (f32x4){bv, bv, bv, bv};
  }

  const int cx = lg ^ (lm & 7);

#pragma unroll
  for (int i = 0; i < 4; ++i) {
    gload16(Ap + (size_t)(i * 64) * K, &smem[0][0][(i * 64 + w * 8) * 64]);
    gload16(Bp + (size_t)(i * 64) * K, &smem[0][1][(i * 64 + w * 8) * 64]);
  }
  __syncthreads();

#pragma unroll
  for (int kt = 0; kt < 4; ++kt) {
    const int cur = kt & 1;
    if (kt + 1 < 4) {
      const int ko = (kt + 1) << 6;
#pragma unroll
      for (int i = 0; i < 4; ++i) {
        gload16(Ap + (size_t)(i * 64) * K + ko, &smem[cur ^ 1][0][(i * 64 + w * 8) * 64]);
        gload16(Bp + (size_t)(i * 64) * K + ko, &smem[cur ^ 1][1][(i * 64 + w * 8) * 64]);
      }
    }
#pragma unroll
    for (int kk = 0; kk < 64; kk += 32) {
      const int ch = (cx ^ (kk >> 3)) * 8;
      bf16x8 af[8], bfr[4];
#pragma unroll
      for (int m = 0; m < 8; ++m)
        af[m] = *(const bf16x8*)&smem[cur][0][(wr * 128 + m * 16 + lm) * 64 + ch];
#pragma unroll
      for (int n = 0; n < 4; ++n)
        bfr[n] = *(const bf16x8*)&smem[cur][1][(wn * 64 + n * 16 + lm) * 64 + ch];
#pragma unroll
      for (int m = 0; m < 8; ++m)
#pragma unroll
        for (int n = 0; n < 4; ++n)
          acc[m][n] = __builtin_amdgcn_mfma_f32_16x16x32_bf16(af[m], bfr[n], acc[m][n], 0, 0, 0);
    }
    if (kt + 1 < 4) __syncthreads();
  }

  // ---- fused epilogue: two 128-row passes; one wave per row ----
  float* Lf = (float*)smem;  // 128 x 256 fp32 = 128 KB
  const float4 g4 = *(const float4*)(g2 + l * 4);
  const float4 bb4 = *(const float4*)(b2 + l * 4);
#pragma unroll
  for (int h = 0; h < 2; ++h) {
    __syncthreads();
    if (wr == h) {
#pragma unroll
      for (int m = 0; m < 8; ++m)
#pragma unroll
        for (int n = 0; n < 4; ++n) {
          const int col = wn * 64 + n * 16 + lm;
#pragma unroll
          for (int r = 0; r < 4; ++r) {
            const int rowl = m * 16 + lg * 4 + r;  // (rowl>>2)&3 == lg
            Lf[rowl * 256 + (col ^ (lg << 4))] = acc[m][n][r];
          }
        }
    }
    __syncthreads();
#pragma unroll
    for (int it = 0; it < 16; ++it) {
      const int rowl = it * 8 + w;
      const int sc = (l * 4) ^ (((rowl >> 2) & 3) << 4);
      float4 v = *(const float4*)&Lf[rowl * 256 + sc];
      // src window-token -> dst natural token (inverse of ln1's gather)
      const int src = m0 + h * 128 + rowl;
      const int bb = src >> 14, wi = (src >> 6) & 255, n = src & 63;
      const int hy = ((wi >> 4) * 8 + (n >> 3) + 4) & 127;
      const int wx = ((wi & 15) * 8 + (n & 7) + 4) & 127;
      const size_t dst = ((size_t)(bb << 14) + hy * 128 + wx) * 256;
      float4 xv = *(const float4*)(x + dst + l * 4);
      const float y0 = xv.x + v.x, y1 = xv.y + v.y;
      const float y2 = xv.z + v.z, y3 = xv.w + v.w;
      *(float4*)(out + dst + l * 4) = make_float4(y0, y1, y2, y3);
      float s = y0 + y1 + y2 + y3;
#pragma unroll
      for (int off = 32; off; off >>= 1) s += __shfl_xor(s, off);
      const float mean = s * (1.f / 256.f);
      const float d0 = y0 - mean, d1 = y1 - mean, d2 = y2 - mean, d3 = y3 - mean;
      float vv = d0 * d0 + d1 * d1 + d2 * d2 + d3 * d3;
#pragma unroll
      for (int off = 32; off; off >>= 1) vv += __shfl_xor(vv, off);
      const float rs = rsqrtf(vv * (1.f / 256.f) + 1e-5f);
      uint2 outv;
      outv.x = packbf2(d0 * rs * g4.x + bb4.x, d1 * rs * g4.y + bb4.y);
      outv.y = packbf2(d2 * rs * g4.z + bb4.z, d3 * rs * g4.w + bb4.w);
      *(uint2*)(h2 + dst + l * 4) = outv;
    }
  }
}

// ---------------- windowed attention, MFMA (16x16x32, verified layout) ----------------
__global__ __launch_bounds__(256) void attn_mfma(
    const unsigned short* __restrict__ qkv, const float* __restrict__ rpb,
    unsigned short* __restrict__ o) {
  __shared__ float rps[16][226];                      // [head][225 bias values]
  __shared__ __align__(16) unsigned short Pl[4][64][72];  // per-wave P [query][key]
  const int win = blockIdx.x;
  const int wh = (win >> 4) & 15, ww = win & 15;
  const int t = threadIdx.x, wv = t >> 6, l = t & 63;
  const int lg = l >> 4, lm = l & 15;
  const unsigned short* base = qkv + (size_t)win * 64 * 768;

  // rpb[idx][h], 3600 floats: vectorized float4 load (900 quads)
  for (int i4 = t; i4 < 900; i4 += 256) {
    const float4 v = *(const float4*)(rpb + i4 * 4);
    const int i = i4 * 4;
    const int r0 = i & 15, c = i >> 4;  // (i&15)<=12 so r0..r0+3 share c
    rps[r0][c] = v.x; rps[r0 + 1][c] = v.y;
    rps[r0 + 2][c] = v.z; rps[r0 + 3][c] = v.w;
  }
  __syncthreads();

  const bool eH = (wh == 15), eW = (ww == 15);
  const bool edge = eH || eW;

  int qv[4], liq[4];
#pragma unroll
  for (int nt = 0; nt < 4; ++nt) {
    const int qn = nt * 16 + lm, ri = qn >> 3, ci = qn & 7;
    qv[nt] = ri * 15 + ci;
    liq[nt] = (eH ? (ri < 4 ? 1 : 2) : 0) * 3 + (eW ? (ci < 4 ? 1 : 2) : 0);
  }
  int kv[4][4], ljk[4][4];
#pragma unroll
  for (int mt = 0; mt < 4; ++mt)
#pragma unroll
    for (int r = 0; r < 4; ++r) {
      const int kn = mt * 16 + 4 * lg + r, rj = kn >> 3, cj = kn & 7;
      kv[mt][r] = rj * 15 + cj;
      ljk[mt][r] = (eH ? (rj < 4 ? 1 : 2) : 0) * 3 + (eW ? (cj < 4 ? 1 : 2) : 0);
    }

  const bf16x8 zf = {0, 0, 0, 0, 0, 0, 0, 0};

#pragma unroll 1
  for (int hi = 0; hi < 4; ++hi) {
    const int h = wv * 4 + hi;
    bf16x8 kf[4], qf[4];
#pragma unroll
    for (int i = 0; i < 4; ++i) {
      kf[i] = (lg < 2)
          ? *(const bf16x8*)(base + (size_t)(i * 16 + lm) * 768 + 256 + h * 16 + lg * 8)
          : zf;
      qf[i] = (lg < 2)
          ? *(const bf16x8*)(base + (size_t)(i * 16 + lm) * 768 + h * 16 + lg * 8)
          : zf;
    }
    f32x4 acc[4][4];  // [mt=key tile][nt=query tile]
#pragma unroll
    for (int mt = 0; mt < 4; ++mt)
#pragma unroll
      for (int nt = 0; nt < 4; ++nt)
        acc[mt][nt] = (f32x4){0.f, 0.f, 0.f, 0.f};
#pragma unroll
    for (int mt = 0; mt < 4; ++mt)
#pragma unroll
      for (int nt = 0; nt < 4; ++nt)
        acc[mt][nt] = __builtin_amdgcn_mfma_f32_16x16x32_bf16(kf[mt], qf[nt], acc[mt][nt], 0, 0, 0);

#pragma unroll
    for (int nt = 0; nt < 4; ++nt) {
      float mx = -1e30f;
#pragma unroll
      for (int mt = 0; mt < 4; ++mt)
#pragma unroll
        for (int r = 0; r < 4; ++r) {
          float s = acc[mt][nt][r] + rps[h][qv[nt] - kv[mt][r] + 112];
          if (edge) s += (liq[nt] == ljk[mt][r]) ? 0.f : -100.f;
          acc[mt][nt][r] = s;
          mx = fmaxf(mx, s);
        }
      mx = fmaxf(mx, __shfl_xor(mx, 16));
      mx = fmaxf(mx, __shfl_xor(mx, 32));
      float sum = 0.f;
#pragma unroll
      for (int mt = 0; mt < 4; ++mt)
#pragma unroll
        for (int r = 0; r < 4; ++r) {
          const float p = __expf(acc[mt][nt][r] - mx);
          acc[mt][nt][r] = p;
          sum += p;
        }
      sum += __shfl_xor(sum, 16);
      sum += __shfl_xor(sum, 32);
      const float inv = 1.f / sum;
      const int qn = nt * 16 + lm;
#pragma unroll
      for (int mt = 0; mt < 4; ++mt) {
        uint2 pk;
        pk.x = packbf2(acc[mt][nt][0] * inv, acc[mt][nt][1] * inv);
        pk.y = packbf2(acc[mt][nt][2] * inv, acc[mt][nt][3] * inv);
        *(uint2*)&Pl[wv][qn][mt * 16 + 4 * lg] = pk;
      }
    }

    f32x4 oacc[4];
#pragma unroll
    for (int mt = 0; mt < 4; ++mt) oacc[mt] = (f32x4){0.f, 0.f, 0.f, 0.f};
#pragma unroll
    for (int kk = 0; kk < 2; ++kk) {
      bf16x8 vf;
#pragma unroll
      for (int j = 0; j < 8; ++j)
        vf[j] = (short)base[(size_t)(kk * 32 + lg * 8 + j) * 768 + 512 + h * 16 + lm];
#pragma unroll
      for (int mt = 0; mt < 4; ++mt) {
        bf16x8 pf = *(const bf16x8*)&Pl[wv][mt * 16 + lm][kk * 32 + lg * 8];
        oacc[mt] = __builtin_amdgcn_mfma_f32_16x16x32_bf16(pf, vf, oacc[mt], 0, 0, 0);
      }
    }
#pragma unroll
    for (int mt = 0; mt < 4; ++mt)
#pragma unroll
      for (int r = 0; r < 4; ++r)
        o[((size_t)win * 64 + mt * 16 + 4 * lg + r) * 256 + h * 16 + lm] = f2bf(oacc[mt][r]);
  }
}

// ---------------- launch ----------------

extern "C" void kernel_launch(void* const* d_in, const int* in_sizes, int n_in,
                              void* d_out, int out_size, void* d_ws, size_t ws_size,
                              hipStream_t stream) {
  const float* x = (const float*)d_in[0];
  const float* ln1g = (const float*)d_in[1];
  const float* ln1b = (const float*)d_in[2];
  const float* qw = (const float*)d_in[3];
  const float* qb = (const float*)d_in[4];
  const float* kw = (const float*)d_in[5];
  const float* kb = (const float*)d_in[6];
  const float* vw = (const float*)d_in[7];
  const float* vb = (const float*)d_in[8];
  const float* rpb = (const float*)d_in[9];
  const float* pw = (const float*)d_in[10];
  const float* pb = (const float*)d_in[11];
  const float* ln2g = (const float*)d_in[12];
  const float* ln2b = (const float*)d_in[13];
  const float* f1w = (const float*)d_in[14];
  const float* f1b = (const float*)d_in[15];
  const float* f2w = (const float*)d_in[16];
  const float* f2b = (const float*)d_in[17];
  float* out = (float*)d_out;

  // workspace layout (lifetime-reused 64MiB slots):
  //   S0: hwin(ln1 out) -> h2 ; S1-3: qkv ; S4: o(attn out) ;
  //   g1 = S1-4 (qkv dead after attn, o dead after proj) ; weights at 5*SLOT.
  char* wsb = (char*)d_ws;
  unsigned short* hwin = (unsigned short*)(wsb);
  unsigned short* qkv = (unsigned short*)(wsb + SLOT);
  unsigned short* ovec = (unsigned short*)(wsb + 4 * SLOT);
  unsigned short* g1 = qkv;
  unsigned short* wqkvt = (unsigned short*)(wsb + 5 * SLOT);   // 768*256
  unsigned short* projt = wqkvt + 768 * 256;                   // 256*256
  unsigned short* fc1t = projt + 256 * 256;                    // 1024*256
  unsigned short* fc2t = fc1t + 1024 * 256;                    // 256*1024
  float* bqkv = (float*)(fc2t + 256 * 1024);                   // 768

  build_qkvw<<<768, 256, 0, stream>>>(qw, kw, vw, qb, kb, vb, wqkvt, bqkv);
  wconv_t<<<256, 256, 0, stream>>>(pw, projt, 256, 256);
  wconv_t<<<1024, 256, 0, stream>>>(f1w, fc1t, 256, 1024);
  wconv_t<<<1024, 256, 0, stream>>>(f2w, fc2t, 1024, 256);

  ln1_roll_win<<<32768, 256, 0, stream>>>(x, ln1g, ln1b, hwin);
  // fused QKV: M=131072, N=768, K=256 (q-scale folded into weights)
  gemm128<0, 256, 768, 6><<<6 * 1024, 256, 0, stream>>>(hwin, wqkvt, bqkv, qkv, nullptr);
  attn_mfma<<<2048, 256, 0, stream>>>(qkv, rpb, ovec);  // o -> S4
  // proj + window-reverse + residual + LN2: x2 -> d_out, h2 -> S0
  proj_ln2<<<512, 512, 0, stream>>>(ovec, projt, pb, x, ln2g, ln2b, out, hwin);
  // fc1 + GELU: M=131072, N=1024, K=256
  gemm128<2, 256, 1024, 8><<<8 * 1024, 256, 0, stream>>>(hwin, fc1t, f1b, g1, nullptr);
  // fc2 + residual accumulate into d_out (holds x2): M=131072, N=256, K=1024
  gemm128<3, 1024, 256, 2><<<2 * 1024, 256, 0, stream>>>(g1, fc2t, f2b, nullptr, out);
}

// Round 18
// 663.003 us; speedup vs baseline: 1.0383x; 1.0090x over previous
//
#include <hip/hip_runtime.h>
#include <hip/hip_bf16.h>
#include <stdint.h>

// SwinTransformerBlock: B=8, H=W=128, C=256, NH=16, HD=16, WS=8, SS=4, HID=1024
// Tokens M = 131072, windows = 2048 (64 tokens each), N_qkv = 768.

#define SLOT ((size_t)64 << 20)  // 64 MiB slot (131072 * 256 * 2B)

typedef __attribute__((ext_vector_type(8))) short bf16x8;
typedef __attribute__((ext_vector_type(4))) float f32x4;

union FU { float f; unsigned u; };

__device__ inline float bflo(unsigned p) { FU x; x.u = p << 16; return x.f; }
__device__ inline float bfhi(unsigned p) { FU x; x.u = p & 0xffff0000u; return x.f; }

// native casts: compiler emits v_cvt_(pk_)bf16_f32
__device__ inline unsigned short f2bf(float f) {
  union { __hip_bfloat16 h; unsigned short u; } cv;
  cv.h = __float2bfloat16(f);
  return cv.u;
}
__device__ inline unsigned packbf2(float a, float b) {
  union { unsigned short s[2]; unsigned u; } cv;
  union { __hip_bfloat16 h; unsigned short u; } ca, cb;
  ca.h = __float2bfloat16(a);
  cb.h = __float2bfloat16(b);
  cv.s[0] = ca.u; cv.s[1] = cb.u;
  return cv.u;
}

// sigmoid GELU: x*sigmoid(1.702x); typical err ~0.005 here, well under threshold
__device__ inline float fast_gelu(float v) {
  return v / (1.0f + __expf(-1.702f * v));
}

// async global -> LDS, 16 bytes per lane
__device__ inline void gload16(const void* g, void* l) {
  __builtin_amdgcn_global_load_lds(
      (const __attribute__((address_space(1))) unsigned int*)g,
      (__attribute__((address_space(3))) unsigned int*)l, 16, 0, 0);
}

// ---------------- weight prep (all four conversions in one launch) ----------------
// region 0: qkv concat+transpose (0.25 q-scale folded) -> wt[768][256] + bias
// region 1: proj^T  -> projt[256][256]
// region 2: fc1^T   -> fc1t[1024][256]
// region 3: fc2^T   -> fc2t[256][1024]
__global__ __launch_bounds__(256) void prep_all(
    const float* __restrict__ qw, const float* __restrict__ kw, const float* __restrict__ vw,
    const float* __restrict__ qb, const float* __restrict__ kb, const float* __restrict__ vb,
    const float* __restrict__ pw, const float* __restrict__ f1w, const float* __restrict__ f2w,
    unsigned short* __restrict__ wt, float* __restrict__ bias,
    unsigned short* __restrict__ projt, unsigned short* __restrict__ fc1t,
    unsigned short* __restrict__ fc2t) {
  int i = blockIdx.x * 256 + threadIdx.x;  // over 786432 = 3072 blocks
  if (i < 196608) {                        // qkv: 768*256
    int n = i >> 8, c = i & 255;
    const float* w = (n < 256) ? qw : (n < 512 ? kw : vw);
    const float sc = (n < 256) ? 0.25f : 1.0f;
    wt[i] = f2bf(sc * w[c * 256 + (n & 255)]);
    if (i < 768)
      bias[i] = (i < 256) ? 0.25f * qb[i] : (i < 512 ? kb[i - 256] : vb[i - 512]);
  } else if (i < 262144) {                 // proj: 256*256
    int j = i - 196608;
    int n = j >> 8, c = j & 255;
    projt[j] = f2bf(pw[c * 256 + n]);
  } else if (i < 524288) {                 // fc1: [1024][256] from [256][1024]
    int j = i - 262144;
    int n = j >> 8, c = j & 255;           // n = hidden 0..1023, c = in 0..255
    fc1t[j] = f2bf(f1w[c * 1024 + n]);
  } else if (i < 786432) {                 // fc2: [256][1024] from [1024][256]
    int j = i - 524288;
    int n = j >> 10, c = j & 1023;         // n = out 0..255, c = hidden 0..1023
    fc2t[j] = f2bf(f2w[c * 256 + n]);
  }
}

// ---------------- LN1 + roll + window partition ----------------
__global__ __launch_bounds__(256) void ln1_roll_win(
    const float* __restrict__ x, const float* __restrict__ g, const float* __restrict__ b,
    unsigned short* __restrict__ hwin) {
  const int tok = blockIdx.x * 4 + (threadIdx.x >> 6);
  const int l = threadIdx.x & 63;
  const int n = tok & 63, wi = (tok >> 6) & 255, bb = tok >> 14;
  const int wh = wi >> 4, ww = wi & 15, r = n >> 3, c = n & 7;
  const int hs = (wh * 8 + r + 4) & 127;    // roll(-4)
  const int wsx = (ww * 8 + c + 4) & 127;
  const float* xr = x + ((size_t)bb * 16384 + hs * 128 + wsx) * 256;
  float4 v = *(const float4*)(xr + l * 4);
  float s = v.x + v.y + v.z + v.w;
#pragma unroll
  for (int off = 32; off; off >>= 1) s += __shfl_xor(s, off);
  const float mean = s * (1.f / 256.f);
  const float d0 = v.x - mean, d1 = v.y - mean, d2 = v.z - mean, d3 = v.w - mean;
  float vv = d0 * d0 + d1 * d1 + d2 * d2 + d3 * d3;
#pragma unroll
  for (int off = 32; off; off >>= 1) vv += __shfl_xor(vv, off);
  const float rs = rsqrtf(vv * (1.f / 256.f) + 1e-5f);
  float4 gg = *(const float4*)(g + l * 4);
  float4 bv = *(const float4*)(b + l * 4);
  uint2 outv;
  outv.x = packbf2(d0 * rs * gg.x + bv.x, d1 * rs * gg.y + bv.y);
  outv.y = packbf2(d2 * rs * gg.z + bv.z, d3 * rs * gg.w + bv.w);
  *(uint2*)(hwin + (size_t)tok * 256 + l * 4) = outv;
}

// ---------------- 128x128-tile bf16 MFMA GEMM (r15/r17 structure, best) ----------------
template <int EPI, int K, int N, int NBX>
__global__ __launch_bounds__(256) void gemm128(
    const unsigned short* __restrict__ A, const unsigned short* __restrict__ Bt,
    const float* __restrict__ bias, unsigned short* __restrict__ Cb,
    float* __restrict__ Cf) {
  __shared__ __align__(16) unsigned short smem[2][2][128 * 64];  // 64KB
  const int nwg = gridDim.x;
  const int q = nwg >> 3;
  const int swz = (blockIdx.x & 7) * q + (blockIdx.x >> 3);
  const int m0 = (swz / NBX) * 128;
  const int n0 = (swz % NBX) * 128;

  const int t = threadIdx.x, w = t >> 6, l = t & 63;
  const int lg = l >> 4, lm = l & 15;
  const int wr = w >> 1, wc = w & 1;  // wave quadrant: rows wr*64, cols wc*64

  const int srow = w * 32 + (l >> 3);
  const int scol = ((l & 7) ^ (l >> 3)) * 8;
  const unsigned short* Ap = A + (size_t)(m0 + srow) * K + scol;
  const unsigned short* Bp = Bt + (size_t)(n0 + srow) * K + scol;

  const int cb = n0 + wc * 64 + lm;
  f32x4 acc[4][4];
#pragma unroll
  for (int n = 0; n < 4; ++n) {
    const float bv = bias[cb + n * 16];
#pragma unroll
    for (int m = 0; m < 4; ++m) acc[m][n] = (f32x4){bv, bv, bv, bv};
  }

  constexpr int NT = K >> 6;
  const int cx = lg ^ (lm & 7);  // read-side chunk base

#pragma unroll
  for (int i = 0; i < 4; ++i) {
    gload16(Ap + (size_t)(i * 8) * K, &smem[0][0][(w * 32 + i * 8) * 64]);
    gload16(Bp + (size_t)(i * 8) * K, &smem[0][1][(w * 32 + i * 8) * 64]);
  }
  __syncthreads();

#pragma unroll
  for (int kt = 0; kt < NT; ++kt) {
    const int cur = kt & 1;
    if (kt + 1 < NT) {
      const int ko = (kt + 1) << 6;
#pragma unroll
      for (int i = 0; i < 4; ++i) {
        gload16(Ap + (size_t)(i * 8) * K + ko, &smem[cur ^ 1][0][(w * 32 + i * 8) * 64]);
        gload16(Bp + (size_t)(i * 8) * K + ko, &smem[cur ^ 1][1][(w * 32 + i * 8) * 64]);
      }
    }
#pragma unroll
    for (int kk = 0; kk < 64; kk += 32) {
      const int ch = (cx ^ (kk >> 3)) * 8;
      bf16x8 af[4], bfr[4];
#pragma unroll
      for (int m = 0; m < 4; ++m)
        af[m] = *(const bf16x8*)&smem[cur][0][(wr * 64 + m * 16 + lm) * 64 + ch];
#pragma unroll
      for (int n = 0; n < 4; ++n)
        bfr[n] = *(const bf16x8*)&smem[cur][1][(wc * 64 + n * 16 + lm) * 64 + ch];
#pragma unroll
      for (int m = 0; m < 4; ++m)
#pragma unroll
        for (int n = 0; n < 4; ++n)
          acc[m][n] = __builtin_amdgcn_mfma_f32_16x16x32_bf16(af[m], bfr[n], acc[m][n], 0, 0, 0);
    }
    if (kt + 1 < NT) __syncthreads();
  }

  // ---- epilogue through LDS: 128x128 fp32, col ^= ((row>>2)&3)<<4 ----
  __syncthreads();
  float* Lp = (float*)smem;
#pragma unroll
  for (int m = 0; m < 4; ++m) {
#pragma unroll
    for (int n = 0; n < 4; ++n) {
      const int col = wc * 64 + n * 16 + lm;
#pragma unroll
      for (int r = 0; r < 4; ++r) {
        const int row = wr * 64 + m * 16 + lg * 4 + r;
        Lp[row * 128 + (col ^ (lg << 4))] = acc[m][n][r];
      }
    }
  }
  __syncthreads();
  if (EPI == 3) {
    const int rr0 = w * 32 + (l >> 5);
    const int cg = (l & 31) * 4;
#pragma unroll
    for (int p = 0; p < 16; ++p) {
      const int row = rr0 + p * 2;
      const int sc = cg ^ (((row >> 2) & 3) << 4);
      float4 v = *(const float4*)&Lp[row * 128 + sc];
      float4* op = (float4*)&Cf[(size_t)(m0 + row) * N + n0 + cg];
      float4 o = *op;
      o.x += v.x; o.y += v.y; o.z += v.z; o.w += v.w;
      *op = o;
    }
  } else {
    // widened bf16 path: 8 iters, 2 LDS float4 reads, one uint4 (8 bf16) store
    const int rw0 = w * 32 + (l >> 4);
    const int cg8 = (l & 15) * 8;
#pragma unroll
    for (int p = 0; p < 8; ++p) {
      const int row = rw0 + p * 4;
      const int swzk = ((row >> 2) & 3) << 4;  // wave-uniform
      float4 v0 = *(const float4*)&Lp[row * 128 + (cg8 ^ swzk)];
      float4 v1 = *(const float4*)&Lp[row * 128 + ((cg8 + 4) ^ swzk)];
      if (EPI == 2) {
        v0.x = fast_gelu(v0.x); v0.y = fast_gelu(v0.y);
        v0.z = fast_gelu(v0.z); v0.w = fast_gelu(v0.w);
        v1.x = fast_gelu(v1.x); v1.y = fast_gelu(v1.y);
        v1.z = fast_gelu(v1.z); v1.w = fast_gelu(v1.w);
      }
      uint4 pk4;
      pk4.x = packbf2(v0.x, v0.y);
      pk4.y = packbf2(v0.z, v0.w);
      pk4.z = packbf2(v1.x, v1.y);
      pk4.w = packbf2(v1.z, v1.w);
      *(uint4*)&Cb[(size_t)(m0 + row) * N + n0 + cg8] = pk4;
    }
  }
}

// ---------------- proj + window-reverse + residual + LN2 (fused, proven r12) ----------------
__global__ __launch_bounds__(512, 2) void proj_ln2(
    const unsigned short* __restrict__ A, const unsigned short* __restrict__ Bt,
    const float* __restrict__ bias, const float* __restrict__ x,
    const float* __restrict__ g2, const float* __restrict__ b2,
    float* __restrict__ out, unsigned short* __restrict__ h2) {
  constexpr int K = 256;
  __shared__ __align__(16) unsigned short smem[2][2][256 * 64];  // 128 KB
  const int nwg = gridDim.x;  // 512
  const int q = nwg >> 3;
  const int swz = (blockIdx.x & 7) * q + (blockIdx.x >> 3);
  const int m0 = swz * 256;

  const int t = threadIdx.x, w = t >> 6, l = t & 63;
  const int lg = l >> 4, lm = l & 15;
  const int wr = w >> 2, wn = w & 3;  // wave tile: rows wr*128, cols wn*64

  const int srow = w * 8 + (l >> 3);
  const int scol = ((l & 7) ^ (l >> 3)) * 8;
  const unsigned short* Ap = A + (size_t)(m0 + srow) * K + scol;
  const unsigned short* Bp = Bt + (size_t)srow * K + scol;

  f32x4 acc[8][4];
#pragma unroll
  for (int n = 0; n < 4; ++n) {
    const float bv = bias[wn * 64 + n * 16 + lm];
#pragma unroll
    for (int m = 0; m < 8; ++m) acc[m][n] = (f32x4){bv, bv, bv, bv};
  }

  const int cx = lg ^ (lm & 7);

#pragma unroll
  for (int i = 0; i < 4; ++i) {
    gload16(Ap + (size_t)(i * 64) * K, &smem[0][0][(i * 64 + w * 8) * 64]);
    gload16(Bp + (size_t)(i * 64) * K, &smem[0][1][(i * 64 + w * 8) * 64]);
  }
  __syncthreads();

#pragma unroll
  for (int kt = 0; kt < 4; ++kt) {
    const int cur = kt & 1;
    if (kt + 1 < 4) {
      const int ko = (kt + 1) << 6;
#pragma unroll
      for (int i = 0; i < 4; ++i) {
        gload16(Ap + (size_t)(i * 64) * K + ko, &smem[cur ^ 1][0][(i * 64 + w * 8) * 64]);
        gload16(Bp + (size_t)(i * 64) * K + ko, &smem[cur ^ 1][1][(i * 64 + w * 8) * 64]);
      }
    }
#pragma unroll
    for (int kk = 0; kk < 64; kk += 32) {
      const int ch = (cx ^ (kk >> 3)) * 8;
      bf16x8 af[8], bfr[4];
#pragma unroll
      for (int m = 0; m < 8; ++m)
        af[m] = *(const bf16x8*)&smem[cur][0][(wr * 128 + m * 16 + lm) * 64 + ch];
#pragma unroll
      for (int n = 0; n < 4; ++n)
        bfr[n] = *(const bf16x8*)&smem[cur][1][(wn * 64 + n * 16 + lm) * 64 + ch];
#pragma unroll
      for (int m = 0; m < 8; ++m)
#pragma unroll
        for (int n = 0; n < 4; ++n)
          acc[m][n] = __builtin_amdgcn_mfma_f32_16x16x32_bf16(af[m], bfr[n], acc[m][n], 0, 0, 0);
    }
    if (kt + 1 < 4) __syncthreads();
  }

  // ---- fused epilogue: two 128-row passes; one wave per row ----
  float* Lf = (float*)smem;  // 128 x 256 fp32 = 128 KB
  const float4 g4 = *(const float4*)(g2 + l * 4);
  const float4 bb4 = *(const float4*)(b2 + l * 4);
#pragma unroll
  for (int h = 0; h < 2; ++h) {
    __syncthreads();
    if (wr == h) {
#pragma unroll
      for (int m = 0; m < 8; ++m)
#pragma unroll
        for (int n = 0; n < 4; ++n) {
          const int col = wn * 64 + n * 16 + lm;
#pragma unroll
          for (int r = 0; r < 4; ++r) {
            const int rowl = m * 16 + lg * 4 + r;  // (rowl>>2)&3 == lg
            Lf[rowl * 256 + (col ^ (lg << 4))] = acc[m][n][r];
          }
        }
    }
    __syncthreads();
#pragma unroll
    for (int it = 0; it < 16; ++it) {
      const int rowl = it * 8 + w;
      const int sc = (l * 4) ^ (((rowl >> 2) & 3) << 4);
      float4 v = *(const float4*)&Lf[rowl * 256 + sc];
      // src window-token -> dst natural token (inverse of ln1's gather)
      const int src = m0 + h * 128 + rowl;
      const int bb = src >> 14, wi = (src >> 6) & 255, n = src & 63;
      const int hy = ((wi >> 4) * 8 + (n >> 3) + 4) & 127;
      const int wx = ((wi & 15) * 8 + (n & 7) + 4) & 127;
      const size_t dst = ((size_t)(bb << 14) + hy * 128 + wx) * 256;
      float4 xv = *(const float4*)(x + dst + l * 4);
      const float y0 = xv.x + v.x, y1 = xv.y + v.y;
      const float y2 = xv.z + v.z, y3 = xv.w + v.w;
      *(float4*)(out + dst + l * 4) = make_float4(y0, y1, y2, y3);
      float s = y0 + y1 + y2 + y3;
#pragma unroll
      for (int off = 32; off; off >>= 1) s += __shfl_xor(s, off);
      const float mean = s * (1.f / 256.f);
      const float d0 = y0 - mean, d1 = y1 - mean, d2 = y2 - mean, d3 = y3 - mean;
      float vv = d0 * d0 + d1 * d1 + d2 * d2 + d3 * d3;
#pragma unroll
      for (int off = 32; off; off >>= 1) vv += __shfl_xor(vv, off);
      const float rs = rsqrtf(vv * (1.f / 256.f) + 1e-5f);
      uint2 outv;
      outv.x = packbf2(d0 * rs * g4.x + bb4.x, d1 * rs * g4.y + bb4.y);
      outv.y = packbf2(d2 * rs * g4.z + bb4.z, d3 * rs * g4.w + bb4.w);
      *(uint2*)(h2 + dst + l * 4) = outv;
    }
  }
}

// ---------------- windowed attention, MFMA (16x16x32, verified layout) ----------------
__global__ __launch_bounds__(256) void attn_mfma(
    const unsigned short* __restrict__ qkv, const float* __restrict__ rpb,
    unsigned short* __restrict__ o) {
  __shared__ float rps[16][226];                      // [head][225 bias values]
  __shared__ __align__(16) unsigned short Pl[4][64][72];  // per-wave P [query][key]
  const int win = blockIdx.x;
  const int wh = (win >> 4) & 15, ww = win & 15;
  const int t = threadIdx.x, wv = t >> 6, l = t & 63;
  const int lg = l >> 4, lm = l & 15;
  const unsigned short* base = qkv + (size_t)win * 64 * 768;

  // rpb[idx][h], 3600 floats: vectorized float4 load (900 quads)
  for (int i4 = t; i4 < 900; i4 += 256) {
    const float4 v = *(const float4*)(rpb + i4 * 4);
    const int i = i4 * 4;
    const int r0 = i & 15, c = i >> 4;  // (i&15)<=12 so r0..r0+3 share c
    rps[r0][c] = v.x; rps[r0 + 1][c] = v.y;
    rps[r0 + 2][c] = v.z; rps[r0 + 3][c] = v.w;
  }
  __syncthreads();

  const bool eH = (wh == 15), eW = (ww == 15);
  const bool edge = eH || eW;

  int qv[4], liq[4];
#pragma unroll
  for (int nt = 0; nt < 4; ++nt) {
    const int qn = nt * 16 + lm, ri = qn >> 3, ci = qn & 7;
    qv[nt] = ri * 15 + ci;
    liq[nt] = (eH ? (ri < 4 ? 1 : 2) : 0) * 3 + (eW ? (ci < 4 ? 1 : 2) : 0);
  }
  int kv[4][4], ljk[4][4];
#pragma unroll
  for (int mt = 0; mt < 4; ++mt)
#pragma unroll
    for (int r = 0; r < 4; ++r) {
      const int kn = mt * 16 + 4 * lg + r, rj = kn >> 3, cj = kn & 7;
      kv[mt][r] = rj * 15 + cj;
      ljk[mt][r] = (eH ? (rj < 4 ? 1 : 2) : 0) * 3 + (eW ? (cj < 4 ? 1 : 2) : 0);
    }

  const bf16x8 zf = {0, 0, 0, 0, 0, 0, 0, 0};

#pragma unroll 1
  for (int hi = 0; hi < 4; ++hi) {
    const int h = wv * 4 + hi;
    bf16x8 kf[4], qf[4];
#pragma unroll
    for (int i = 0; i < 4; ++i) {
      kf[i] = (lg < 2)
          ? *(const bf16x8*)(base + (size_t)(i * 16 + lm) * 768 + 256 + h * 16 + lg * 8)
          : zf;
      qf[i] = (lg < 2)
          ? *(const bf16x8*)(base + (size_t)(i * 16 + lm) * 768 + h * 16 + lg * 8)
          : zf;
    }
    f32x4 acc[4][4];  // [mt=key tile][nt=query tile]
#pragma unroll
    for (int mt = 0; mt < 4; ++mt)
#pragma unroll
      for (int nt = 0; nt < 4; ++nt)
        acc[mt][nt] = (f32x4){0.f, 0.f, 0.f, 0.f};
#pragma unroll
    for (int mt = 0; mt < 4; ++mt)
#pragma unroll
      for (int nt = 0; nt < 4; ++nt)
        acc[mt][nt] = __builtin_amdgcn_mfma_f32_16x16x32_bf16(kf[mt], qf[nt], acc[mt][nt], 0, 0, 0);

#pragma unroll
    for (int nt = 0; nt < 4; ++nt) {
      float mx = -1e30f;
#pragma unroll
      for (int mt = 0; mt < 4; ++mt)
#pragma unroll
        for (int r = 0; r < 4; ++r) {
          float s = acc[mt][nt][r] + rps[h][qv[nt] - kv[mt][r] + 112];
          if (edge) s += (liq[nt] == ljk[mt][r]) ? 0.f : -100.f;
          acc[mt][nt][r] = s;
          mx = fmaxf(mx, s);
        }
      mx = fmaxf(mx, __shfl_xor(mx, 16));
      mx = fmaxf(mx, __shfl_xor(mx, 32));
      float sum = 0.f;
#pragma unroll
      for (int mt = 0; mt < 4; ++mt)
#pragma unroll
        for (int r = 0; r < 4; ++r) {
          const float p = __expf(acc[mt][nt][r] - mx);
          acc[mt][nt][r] = p;
          sum += p;
        }
      sum += __shfl_xor(sum, 16);
      sum += __shfl_xor(sum, 32);
      const float inv = 1.f / sum;
      const int qn = nt * 16 + lm;
#pragma unroll
      for (int mt = 0; mt < 4; ++mt) {
        uint2 pk;
        pk.x = packbf2(acc[mt][nt][0] * inv, acc[mt][nt][1] * inv);
        pk.y = packbf2(acc[mt][nt][2] * inv, acc[mt][nt][3] * inv);
        *(uint2*)&Pl[wv][qn][mt * 16 + 4 * lg] = pk;
      }
    }

    f32x4 oacc[4];
#pragma unroll
    for (int mt = 0; mt < 4; ++mt) oacc[mt] = (f32x4){0.f, 0.f, 0.f, 0.f};
#pragma unroll
    for (int kk = 0; kk < 2; ++kk) {
      bf16x8 vf;
#pragma unroll
      for (int j = 0; j < 8; ++j)
        vf[j] = (short)base[(size_t)(kk * 32 + lg * 8 + j) * 768 + 512 + h * 16 + lm];
#pragma unroll
      for (int mt = 0; mt < 4; ++mt) {
        bf16x8 pf = *(const bf16x8*)&Pl[wv][mt * 16 + lm][kk * 32 + lg * 8];
        oacc[mt] = __builtin_amdgcn_mfma_f32_16x16x32_bf16(pf, vf, oacc[mt], 0, 0, 0);
      }
    }
#pragma unroll
    for (int mt = 0; mt < 4; ++mt)
#pragma unroll
      for (int r = 0; r < 4; ++r)
        o[((size_t)win * 64 + mt * 16 + 4 * lg + r) * 256 + h * 16 + lm] = f2bf(oacc[mt][r]);
  }
}

// ---------------- launch ----------------

extern "C" void kernel_launch(void* const* d_in, const int* in_sizes, int n_in,
                              void* d_out, int out_size, void* d_ws, size_t ws_size,
                              hipStream_t stream) {
  const float* x = (const float*)d_in[0];
  const float* ln1g = (const float*)d_in[1];
  const float* ln1b = (const float*)d_in[2];
  const float* qw = (const float*)d_in[3];
  const float* qb = (const float*)d_in[4];
  const float* kw = (const float*)d_in[5];
  const float* kb = (const float*)d_in[6];
  const float* vw = (const float*)d_in[7];
  const float* vb = (const float*)d_in[8];
  const float* rpb = (const float*)d_in[9];
  const float* pw = (const float*)d_in[10];
  const float* pb = (const float*)d_in[11];
  const float* ln2g = (const float*)d_in[12];
  const float* ln2b = (const float*)d_in[13];
  const float* f1w = (const float*)d_in[14];
  const float* f1b = (const float*)d_in[15];
  const float* f2w = (const float*)d_in[16];
  const float* f2b = (const float*)d_in[17];
  float* out = (float*)d_out;

  // workspace layout (lifetime-reused 64MiB slots):
  //   S0: hwin(ln1 out) -> h2 ; S1-3: qkv ; S4: o(attn out) ;
  //   g1 = S1-4 (qkv dead after attn, o dead after proj) ; weights at 5*SLOT.
  char* wsb = (char*)d_ws;
  unsigned short* hwin = (unsigned short*)(wsb);
  unsigned short* qkv = (unsigned short*)(wsb + SLOT);
  unsigned short* ovec = (unsigned short*)(wsb + 4 * SLOT);
  unsigned short* g1 = qkv;
  unsigned short* wqkvt = (unsigned short*)(wsb + 5 * SLOT);   // 768*256
  unsigned short* projt = wqkvt + 768 * 256;                   // 256*256
  unsigned short* fc1t = projt + 256 * 256;                    // 1024*256
  unsigned short* fc2t = fc1t + 1024 * 256;                    // 256*1024
  float* bqkv = (float*)(fc2t + 256 * 1024);                   // 768

  prep_all<<<3072, 256, 0, stream>>>(qw, kw, vw, qb, kb, vb, pw, f1w, f2w,
                                     wqkvt, bqkv, projt, fc1t, fc2t);

  ln1_roll_win<<<32768, 256, 0, stream>>>(x, ln1g, ln1b, hwin);
  // fused QKV: M=131072, N=768, K=256 (q-scale folded into weights)
  gemm128<0, 256, 768, 6><<<6 * 1024, 256, 0, stream>>>(hwin, wqkvt, bqkv, qkv, nullptr);
  attn_mfma<<<2048, 256, 0, stream>>>(qkv, rpb, ovec);  // o -> S4
  // proj + window-reverse + residual + LN2: x2 -> d_out, h2 -> S0
  proj_ln2<<<512, 512, 0, stream>>>(ovec, projt, pb, x, ln2g, ln2b, out, hwin);
  // fc1 + GELU: M=131072, N=1024, K=256
  gemm128<2, 256, 1024, 8><<<8 * 1024, 256, 0, stream>>>(hwin, fc1t, f1b, g1, nullptr);
  // fc2 + residual accumulate into d_out (holds x2): M=131072, N=256, K=1024
  gemm128<3, 1024, 256, 2><<<2 * 1024, 256, 0, stream>>>(g1, fc2t, f2b, nullptr, out);
}